// Round 3
// baseline (529.800 us; speedup 1.0000x reference)
//
#include <hip/hip_runtime.h>
#include <hip/hip_bf16.h>
#include <cstdint>

#define N_ATOMS 100000
#define NFEAT   256
#define NMOL    1024
#define ROWS_PER_UNIT 32
#define N_UNITS 6256   // 2 col-halves * ceil(100096/32) = 2*3128

static constexpr float SCALE_C = 5.992277830325989f;
static constexpr float SHIFT_C = -406274.63784969115f;

typedef __attribute__((ext_vector_type(8))) short short8;    // bf16x8 MFMA operand
typedef __attribute__((ext_vector_type(4))) float float4_t;  // f32x4 accumulator

__device__ __forceinline__ unsigned short f2bf(float x) {
    union { float f; uint32_t u; } v; v.f = x;
    uint32_t r = (v.u + 0x7fffu + ((v.u >> 16) & 1u)) >> 16;
    return (unsigned short)r;
}

__device__ __forceinline__ float silu(float x) {
    return x / (1.0f + __expf(-x));
}

// async global->LDS, 16B/lane; LDS dest wave-uniform, lane i lands at +i*16B
__device__ __forceinline__ void async16(void* lds, const void* g) {
    __builtin_amdgcn_global_load_lds(
        (const __attribute__((address_space(1))) unsigned int*)(uintptr_t)g,
        (__attribute__((address_space(3))) unsigned int*)(uint32_t)(uintptr_t)lds,
        16, 0, 0);
}

// W image layout (prep output; shorts): plane(k>>7)*32768 + n*128 +
//   (((k>>3)&15 ^ (n&15))<<3) + (k&7).
// 256B row stride + 16B-chunk XOR swizzle = R2's verified zero-conflict pattern.
__device__ __forceinline__ short8 wfrag(const unsigned short* Wlds, int n, int kc) {
    return *(const short8*)&Wlds[((kc >> 4) << 15) + n * 128 +
                                 ((((kc & 15) ^ (n & 15)) & 15) << 3)];
}

// per-wave work stealing (no block sync needed; W in LDS is read-only)
__device__ __forceinline__ int steal(int* ctr, int lane) {
    int u = 0;
    if (lane == 0) u = atomicAdd(ctr, 1);
    return __shfl(u, 0);
}

// ---------------------------------------------------------------------------
// Prep: W1,W2 fp32 [k][n] -> bf16 swizzled plane images; init out[]=SHIFT and
// the two work-steal counters.
// ---------------------------------------------------------------------------
__global__ void prep(const float* __restrict__ W1, const float* __restrict__ W2,
                     unsigned short* __restrict__ W1i, unsigned short* __restrict__ W2i,
                     float* __restrict__ out, int* __restrict__ ctrs) {
    int g = blockIdx.x * 256 + threadIdx.x;          // 0 .. 131071
    const float* W = (g < 65536) ? W1 : W2;
    unsigned short* Wi = (g < 65536) ? W1i : W2i;
    int idx = g & 65535;
    int k = idx >> 8, n = idx & 255;
    int kc = (k >> 3) & 15;
    int pos = ((k >> 7) << 15) + n * 128 + (((kc ^ (n & 15)) & 15) << 3) + (k & 7);
    Wi[pos] = f2bf(W[idx]);
    if (g < NMOL) out[g] = SHIFT_C;
    if (g < 2) ctrs[g] = 0;
}

// ---------------------------------------------------------------------------
// Layer 1: H1 = silu(A @ W1 + b1), A fp32 [100000][256].
// 512 thr = 8 waves; full W1 (128 KB) in LDS staged once; each wave streams
// 32-row x 128-col units with K=256 unrolled in registers. No barriers in
// the stream. Swapped MFMA operands (a=W, b=atoms) so each lane's acc holds
// 4 consecutive H1 cols -> 8B stores.
// ---------------------------------------------------------------------------
__global__ __launch_bounds__(512)
void mlp1(const float* __restrict__ A, const unsigned short* __restrict__ Wimg,
          const float* __restrict__ b1, unsigned short* __restrict__ H1,
          int* __restrict__ ctr) {
    __shared__ unsigned short Wlds[65536];   // 128 KB

    const int tid = threadIdx.x;
    const int w = tid >> 6, lane = tid & 63;
    const int fl = lane & 15, qd = lane >> 4;

#pragma unroll
    for (int i = 0; i < 16; ++i)
        async16(&Wlds[(w * 16 + i) * 512], Wimg + (w * 16 + i) * 512 + lane * 8);
    __syncthreads();

    for (;;) {
        int u = steal(ctr, lane);
        if (u >= N_UNITS) break;
        const int nh = (u & 1) * 128;
        const int rbase = (u >> 1) * ROWS_PER_UNIT;

        float4_t acc[8][2] = {};   // [col-tile][row-tile]
#pragma unroll
        for (int s = 0; s < 8; ++s) {
            const int kc = s * 4 + qd;
            short8 af[2];
#pragma unroll
            for (int j = 0; j < 2; ++j) {
                int row = rbase + j * 16 + fl;
                float4 v0 = {0.f, 0.f, 0.f, 0.f}, v1 = {0.f, 0.f, 0.f, 0.f};
                if (row < N_ATOMS) {
                    const float* p = A + (size_t)row * 256 + s * 32 + qd * 8;
                    v0 = *(const float4*)p;
                    v1 = *(const float4*)(p + 4);
                }
                af[j][0] = f2bf(v0.x); af[j][1] = f2bf(v0.y);
                af[j][2] = f2bf(v0.z); af[j][3] = f2bf(v0.w);
                af[j][4] = f2bf(v1.x); af[j][5] = f2bf(v1.y);
                af[j][6] = f2bf(v1.z); af[j][7] = f2bf(v1.w);
            }
#pragma unroll
            for (int i = 0; i < 8; ++i) {
                short8 wf = wfrag(Wlds, nh + i * 16 + fl, kc);
#pragma unroll
                for (int j = 0; j < 2; ++j)
                    acc[i][j] = __builtin_amdgcn_mfma_f32_16x16x32_bf16(
                        wf, af[j], acc[i][j], 0, 0, 0);
            }
        }
        // acc[i][j]: atom = rbase + j*16 + fl, col = nh + i*16 + qd*4 + r
#pragma unroll
        for (int i = 0; i < 8; ++i) {
            int nb = nh + i * 16 + qd * 4;
            float4 b4 = *(const float4*)&b1[nb];
#pragma unroll
            for (int j = 0; j < 2; ++j) {
                int atom = rbase + j * 16 + fl;
                if (atom < N_ATOMS) {
                    ushort4 o;
                    o.x = f2bf(silu(acc[i][j][0] + b4.x));
                    o.y = f2bf(silu(acc[i][j][1] + b4.y));
                    o.z = f2bf(silu(acc[i][j][2] + b4.z));
                    o.w = f2bf(silu(acc[i][j][3] + b4.w));
                    *(ushort4*)&H1[(size_t)atom * 256 + nb] = o;
                }
            }
        }
    }
}

// ---------------------------------------------------------------------------
// Layer 2+3+pool: out[mol] += SCALE*(silu(H1@W2+b2).W3 + b3). Same streaming
// structure, natural operand order; epilogue: silu, dot W3, shfl-reduce over
// the 16 col-lanes, atomicAdd per atom.
// ---------------------------------------------------------------------------
__global__ __launch_bounds__(512)
void mlp2(const unsigned short* __restrict__ H1, const unsigned short* __restrict__ Wimg,
          const float* __restrict__ b2, const float* __restrict__ W3,
          const float* __restrict__ b3, const int* __restrict__ batch,
          float* __restrict__ out, int* __restrict__ ctr) {
    __shared__ unsigned short Wlds[65536];   // 128 KB

    const int tid = threadIdx.x;
    const int w = tid >> 6, lane = tid & 63;
    const int fl = lane & 15, qd = lane >> 4;

#pragma unroll
    for (int i = 0; i < 16; ++i)
        async16(&Wlds[(w * 16 + i) * 512], Wimg + (w * 16 + i) * 512 + lane * 8);
    __syncthreads();

    const float b3v = b3[0];

    for (;;) {
        int u = steal(ctr, lane);
        if (u >= N_UNITS) break;
        const int nh = (u & 1) * 128;
        const int rbase = (u >> 1) * ROWS_PER_UNIT;

        float4_t acc[2][8] = {};   // [row-tile][col-tile]
#pragma unroll
        for (int s = 0; s < 8; ++s) {
            const int kc = s * 4 + qd;
            short8 hf[2];
#pragma unroll
            for (int i = 0; i < 2; ++i) {
                int row = rbase + i * 16 + fl;
                if (row < N_ATOMS)
                    hf[i] = *(const short8*)&H1[(size_t)row * 256 + s * 32 + qd * 8];
                else
                    hf[i] = (short8){0, 0, 0, 0, 0, 0, 0, 0};
            }
#pragma unroll
            for (int j = 0; j < 8; ++j) {
                short8 wf = wfrag(Wlds, nh + j * 16 + fl, kc);
#pragma unroll
                for (int i = 0; i < 2; ++i)
                    acc[i][j] = __builtin_amdgcn_mfma_f32_16x16x32_bf16(
                        hf[i], wf, acc[i][j], 0, 0, 0);
            }
        }
        // acc[i][j]: atom = rbase + i*16 + qd*4 + r, col = nh + j*16 + fl
        float rs[2][4] = {};
#pragma unroll
        for (int j = 0; j < 8; ++j) {
            int col = nh + j * 16 + fl;
            float bb = b2[col];
            float w3 = W3[col];
#pragma unroll
            for (int i = 0; i < 2; ++i)
#pragma unroll
                for (int r = 0; r < 4; ++r)
                    rs[i][r] += silu(acc[i][j][r] + bb) * w3;
        }
#pragma unroll
        for (int i = 0; i < 2; ++i)
#pragma unroll
            for (int r = 0; r < 4; ++r) {
                float v = rs[i][r];
                v += __shfl_xor(v, 1);
                v += __shfl_xor(v, 2);
                v += __shfl_xor(v, 4);
                v += __shfl_xor(v, 8);
                rs[i][r] = v;
            }
        if (fl == 0) {
#pragma unroll
            for (int i = 0; i < 2; ++i)
#pragma unroll
                for (int r = 0; r < 4; ++r) {
                    int atom = rbase + i * 16 + qd * 4 + r;
                    if (atom < N_ATOMS) {
                        float v = rs[i][r] + (nh == 0 ? b3v : 0.0f);
                        atomicAdd(&out[batch[atom]], v * SCALE_C);
                    }
                }
        }
    }
}

// ---------------------------------------------------------------------------
extern "C" void kernel_launch(void* const* d_in, const int* in_sizes, int n_in,
                              void* d_out, int out_size, void* d_ws, size_t ws_size,
                              hipStream_t stream) {
    const float* A     = (const float*)d_in[0];
    const int*   batch = (const int*)d_in[1];
    const float* W1    = (const float*)d_in[2];
    const float* b1    = (const float*)d_in[3];
    const float* W2    = (const float*)d_in[4];
    const float* b2    = (const float*)d_in[5];
    const float* W3    = (const float*)d_in[6];
    const float* b3    = (const float*)d_in[7];
    float* out = (float*)d_out;

    unsigned short* H1  = (unsigned short*)d_ws;            // 100096*256 bf16
    unsigned short* W1i = H1 + (size_t)100096 * NFEAT;      // 65536 shorts
    unsigned short* W2i = W1i + 65536;                      // 65536 shorts
    int* ctrs = (int*)(W2i + 65536);                        // [2]

    prep<<<dim3(512), 256, 0, stream>>>(W1, W2, W1i, W2i, out, ctrs);
    mlp1<<<dim3(256), 512, 0, stream>>>(A, W1i, b1, H1, &ctrs[0]);
    mlp2<<<dim3(256), 512, 0, stream>>>(H1, W2i, b2, W3, b3, batch, out, &ctrs[1]);
}

// Round 4
// 280.044 us; speedup vs baseline: 1.8918x; 1.8918x over previous
//
#include <hip/hip_runtime.h>
#include <hip/hip_bf16.h>
#include <cstdint>

#define N_ATOMS 100000
#define NFEAT   256
#define NMOL    1024
#define ROWS    32
#define UNITS   3128    // 100096 / 32
#define NBLK    256

static constexpr float SCALE_C = 5.992277830325989f;
static constexpr float SHIFT_C = -406274.63784969115f;

typedef __attribute__((ext_vector_type(8))) short short8;    // bf16x8 MFMA operand
typedef __attribute__((ext_vector_type(4))) float float4_t;  // f32x4 accumulator

__device__ __forceinline__ unsigned short f2bf(float x) {
    union { float f; uint32_t u; } v; v.f = x;
    uint32_t r = (v.u + 0x7fffu + ((v.u >> 16) & 1u)) >> 16;
    return (unsigned short)r;
}

// pack two fp32 -> two bf16 (round-half-up) in ONE v_perm after bias adds
__device__ __forceinline__ uint32_t pk(float lo, float hi) {
    union { float f; uint32_t u; } a, b; a.f = lo; b.f = hi;
    return __builtin_amdgcn_perm(b.u + 0x8000u, a.u + 0x8000u, 0x07060302u);
}

__device__ __forceinline__ float silu(float x) {
    return x / (1.0f + __expf(-x));
}

// async global->LDS, 16B/lane; LDS dest wave-uniform, lane i lands at +i*16B
__device__ __forceinline__ void async16(void* lds, const void* g) {
    __builtin_amdgcn_global_load_lds(
        (const __attribute__((address_space(1))) unsigned int*)(uintptr_t)g,
        (__attribute__((address_space(3))) unsigned int*)(uint32_t)(uintptr_t)lds,
        16, 0, 0);
}

// W image layout (prep output; shorts): plane(k>>7)*32768 + n*128 +
//   (((k>>3)&15 ^ (n&15))<<3) + (k&7).  Verified zero-conflict in R2/R3.
__device__ __forceinline__ short8 wfrag(const unsigned short* Wlds, int n, int kc) {
    return *(const short8*)&Wlds[((kc >> 4) << 15) + n * 128 +
                                 ((((kc & 15) ^ (n & 15)) & 15) << 3)];
}

// ---------------------------------------------------------------------------
// Prep: W1,W2 fp32 [k][n] -> bf16 swizzled plane images; init out[] = SHIFT.
// ---------------------------------------------------------------------------
__global__ void prep(const float* __restrict__ W1, const float* __restrict__ W2,
                     unsigned short* __restrict__ W1i, unsigned short* __restrict__ W2i,
                     float* __restrict__ out) {
    int g = blockIdx.x * 256 + threadIdx.x;          // 0 .. 131071
    const float* W = (g < 65536) ? W1 : W2;
    unsigned short* Wi = (g < 65536) ? W1i : W2i;
    int idx = g & 65535;
    int k = idx >> 8, n = idx & 255;
    int kc = (k >> 3) & 15;
    int pos = ((k >> 7) << 15) + n * 128 + (((kc ^ (n & 15)) & 15) << 3) + (k & 7);
    Wi[pos] = f2bf(W[idx]);
    if (g < NMOL) out[g] = SHIFT_C;
}

// ---------------------------------------------------------------------------
// Layer 1: H1 = silu(A @ W1 + b1), A fp32. 8 waves/block, W1 (128 KB) in LDS
// staged once. Units = 32 rows x 256 cols, K=256 unrolled; intra-block LDS
// work-steal counter (ds_atomic), inter-block static stripe u = blk + 256*t.
// Swapped MFMA operands so each lane's acc holds 4 consecutive H1 cols.
// ---------------------------------------------------------------------------
__global__ __launch_bounds__(512, 2)
void mlp1(const float* __restrict__ A, const unsigned short* __restrict__ Wimg,
          const float* __restrict__ b1, unsigned short* __restrict__ H1) {
    __shared__ unsigned short Wlds[65536];   // 128 KB
    __shared__ int uctr;

    const int tid = threadIdx.x;
    const int w = tid >> 6, lane = tid & 63;
    const int fl = lane & 15, qd = lane >> 4;

#pragma unroll
    for (int i = 0; i < 16; ++i)
        async16(&Wlds[(w * 16 + i) * 512], Wimg + (w * 16 + i) * 512 + lane * 8);
    if (tid == 0) uctr = 0;
    __syncthreads();

    for (;;) {
        int t = 0;
        if (lane == 0) t = atomicAdd(&uctr, 1);   // LDS atomic — intra-block only
        t = __shfl(t, 0);
        int u = blockIdx.x + (t << 8);
        if (u >= UNITS) break;
        const int rbase = u * ROWS;

        float4_t acc[16][2] = {};   // [col-tile][row-tile]
#pragma unroll
        for (int s = 0; s < 8; ++s) {
            const int kc = s * 4 + qd;
            short8 af[2];
#pragma unroll
            for (int j = 0; j < 2; ++j) {
                int row = rbase + j * 16 + fl;
                float4 v0 = {0.f, 0.f, 0.f, 0.f}, v1 = {0.f, 0.f, 0.f, 0.f};
                if (row < N_ATOMS) {
                    const float* p = A + (size_t)row * 256 + s * 32 + qd * 8;
                    v0 = *(const float4*)p;
                    v1 = *(const float4*)(p + 4);
                }
                union { uint32_t u4[4]; short8 s8; } cv;
                cv.u4[0] = pk(v0.x, v0.y); cv.u4[1] = pk(v0.z, v0.w);
                cv.u4[2] = pk(v1.x, v1.y); cv.u4[3] = pk(v1.z, v1.w);
                af[j] = cv.s8;
            }
#pragma unroll
            for (int i = 0; i < 16; ++i) {
                short8 wf = wfrag(Wlds, i * 16 + fl, kc);
                acc[i][0] = __builtin_amdgcn_mfma_f32_16x16x32_bf16(wf, af[0], acc[i][0], 0, 0, 0);
                acc[i][1] = __builtin_amdgcn_mfma_f32_16x16x32_bf16(wf, af[1], acc[i][1], 0, 0, 0);
            }
        }
        // acc[i][j]: atom = rbase + j*16 + fl, col = i*16 + qd*4 + r
#pragma unroll
        for (int i = 0; i < 16; ++i) {
            int nb = i * 16 + qd * 4;
            float4 b4 = *(const float4*)&b1[nb];
#pragma unroll
            for (int j = 0; j < 2; ++j) {
                int atom = rbase + j * 16 + fl;
                if (atom < N_ATOMS) {
                    uint2 o;
                    o.x = pk(silu(acc[i][j][0] + b4.x), silu(acc[i][j][1] + b4.y));
                    o.y = pk(silu(acc[i][j][2] + b4.z), silu(acc[i][j][3] + b4.w));
                    *(uint2*)&H1[(size_t)atom * 256 + nb] = o;
                }
            }
        }
    }
}

// ---------------------------------------------------------------------------
// Layer 2+3+pool: out[mol] += SCALE*(silu(H1@W2+b2).W3 + b3). Same streaming
// structure, natural operand order; epilogue: silu, dot W3, fl-butterfly
// reduce, one atomicAdd per atom (spread addresses — proven cheap in R2).
// ---------------------------------------------------------------------------
__global__ __launch_bounds__(512, 2)
void mlp2(const unsigned short* __restrict__ H1, const unsigned short* __restrict__ Wimg,
          const float* __restrict__ b2, const float* __restrict__ W3,
          const float* __restrict__ b3, const int* __restrict__ batch,
          float* __restrict__ out) {
    __shared__ unsigned short Wlds[65536];   // 128 KB
    __shared__ int uctr;

    const int tid = threadIdx.x;
    const int w = tid >> 6, lane = tid & 63;
    const int fl = lane & 15, qd = lane >> 4;

#pragma unroll
    for (int i = 0; i < 16; ++i)
        async16(&Wlds[(w * 16 + i) * 512], Wimg + (w * 16 + i) * 512 + lane * 8);
    if (tid == 0) uctr = 0;
    __syncthreads();

    const float b3v = b3[0];
    // per-lane bias/W3 for cols i*16 + fl (fixed across units)
    float bbv[16], w3v[16];
#pragma unroll
    for (int i = 0; i < 16; ++i) {
        bbv[i] = b2[i * 16 + fl];
        w3v[i] = W3[i * 16 + fl];
    }

    for (;;) {
        int t = 0;
        if (lane == 0) t = atomicAdd(&uctr, 1);
        t = __shfl(t, 0);
        int u = blockIdx.x + (t << 8);
        if (u >= UNITS) break;
        const int rbase = u * ROWS;

        float4_t acc[2][16] = {};   // [row-tile][col-tile]
#pragma unroll
        for (int s = 0; s < 8; ++s) {
            const int kc = s * 4 + qd;
            short8 hf[2];
#pragma unroll
            for (int j = 0; j < 2; ++j) {
                int row = rbase + j * 16 + fl;
                if (row < N_ATOMS)
                    hf[j] = *(const short8*)&H1[(size_t)row * 256 + s * 32 + qd * 8];
                else
                    hf[j] = (short8){0, 0, 0, 0, 0, 0, 0, 0};
            }
#pragma unroll
            for (int i = 0; i < 16; ++i) {
                short8 wf = wfrag(Wlds, i * 16 + fl, kc);
                acc[0][i] = __builtin_amdgcn_mfma_f32_16x16x32_bf16(hf[0], wf, acc[0][i], 0, 0, 0);
                acc[1][i] = __builtin_amdgcn_mfma_f32_16x16x32_bf16(hf[1], wf, acc[1][i], 0, 0, 0);
            }
        }
        // acc[j][i]: atom = rbase + j*16 + qd*4 + r, col = i*16 + fl
        float rs[2][4] = {};
#pragma unroll
        for (int i = 0; i < 16; ++i) {
#pragma unroll
            for (int j = 0; j < 2; ++j)
#pragma unroll
                for (int r = 0; r < 4; ++r)
                    rs[j][r] += silu(acc[j][i][r] + bbv[i]) * w3v[i];
        }
#pragma unroll
        for (int j = 0; j < 2; ++j)
#pragma unroll
            for (int r = 0; r < 4; ++r) {
                float v = rs[j][r];
                v += __shfl_xor(v, 1);
                v += __shfl_xor(v, 2);
                v += __shfl_xor(v, 4);
                v += __shfl_xor(v, 8);
                rs[j][r] = v;
            }
        // butterfly = allreduce over fl; lane fl == j*4+r posts atom's add
#pragma unroll
        for (int j = 0; j < 2; ++j)
#pragma unroll
            for (int r = 0; r < 4; ++r)
                if (fl == j * 4 + r) {
                    int atom = rbase + j * 16 + qd * 4 + r;
                    if (atom < N_ATOMS)
                        atomicAdd(&out[batch[atom]], (rs[j][r] + b3v) * SCALE_C);
                }
    }
}

// ---------------------------------------------------------------------------
extern "C" void kernel_launch(void* const* d_in, const int* in_sizes, int n_in,
                              void* d_out, int out_size, void* d_ws, size_t ws_size,
                              hipStream_t stream) {
    const float* A     = (const float*)d_in[0];
    const int*   batch = (const int*)d_in[1];
    const float* W1    = (const float*)d_in[2];
    const float* b1    = (const float*)d_in[3];
    const float* W2    = (const float*)d_in[4];
    const float* b2    = (const float*)d_in[5];
    const float* W3    = (const float*)d_in[6];
    const float* b3    = (const float*)d_in[7];
    float* out = (float*)d_out;

    unsigned short* H1  = (unsigned short*)d_ws;            // 100096*256 bf16
    unsigned short* W1i = H1 + (size_t)100096 * NFEAT;      // 65536 shorts
    unsigned short* W2i = W1i + 65536;                      // 65536 shorts

    prep<<<dim3(512), 256, 0, stream>>>(W1, W2, W1i, W2i, out);
    mlp1<<<dim3(NBLK), 512, 0, stream>>>(A, W1i, b1, H1);
    mlp2<<<dim3(NBLK), 512, 0, stream>>>(H1, W2i, b2, W3, b3, batch, out);
}